// Round 4
// baseline (797.266 us; speedup 1.0000x reference)
//
#include <hip/hip_runtime.h>
#include <hip/hip_bf16.h>

#define B_ 64
#define N_ 4096
#define C_ 256
#define K_ 8
#define M_ (B_*N_)
#define ITERS_ 3
#define SCALE_ 0.0625f
#define EPS_ 1e-8f

typedef __attribute__((ext_vector_type(4))) float f32x4;
typedef __attribute__((ext_vector_type(8))) unsigned short ushort8;

__device__ __forceinline__ unsigned short f2bf(float f){
    union { float f; unsigned u; } v; v.f = f;
    unsigned r = v.u + 0x7fffu + ((v.u >> 16) & 1u);
    return (unsigned short)(r >> 16);
}
__device__ __forceinline__ float bf2f(unsigned short h){
    union { unsigned u; float f; } v; v.u = ((unsigned)h) << 16;
    return v.f;
}

// ---------------- prep: slots init + WkT transpose ----------------
__global__ void prep_kernel(const float* __restrict__ mu, const float* __restrict__ lsig,
                            const float* __restrict__ noise, const float* __restrict__ Wk,
                            float* __restrict__ slots, float* __restrict__ WkT){
    int idx = blockIdx.x * 256 + threadIdx.x;   // 0..131071
    int c = idx & 255, i = (idx >> 8) & 7;
    slots[idx] = mu[c] + expf(lsig[c]) * noise[i*256 + c];
    if (idx < 65536){
        int cc = idx >> 8, d = idx & 255;       // WkT[cc][d] = Wk[d][cc]
        WkT[idx] = Wk[(size_t)d*256 + cc];
    }
}

// ---------------- x -> x_hat bf16, tiled layout XH[jt][o(0..31)][rloc(0..255)][8] ----------------
__global__ __launch_bounds__(256)
void ln_kernel(const float* __restrict__ x, const float* __restrict__ g,
               const float* __restrict__ bta, unsigned short* __restrict__ XH){
    const int t = threadIdx.x;
    const int row = blockIdx.x*32 + (t >> 3), sl = t & 7;
    const float* xr = x + (size_t)row*C_ + sl*32;
    float v[32];
    #pragma unroll
    for (int q = 0; q < 8; ++q) *(float4*)&v[q*4] = *(const float4*)(xr + q*4);
    float sum = 0.f, sq = 0.f;
    #pragma unroll
    for (int e = 0; e < 32; ++e){ sum += v[e]; sq += v[e]*v[e]; }
    #pragma unroll
    for (int m = 1; m < 8; m <<= 1){ sum += __shfl_xor(sum, m); sq += __shfl_xor(sq, m); }
    float mean = sum * (1.f/256.f);
    float rstd = rsqrtf(sq * (1.f/256.f) - mean*mean + 1e-5f);
    const int jt = row >> 8, rloc = row & 255;
    #pragma unroll
    for (int u = 0; u < 4; ++u){
        float4 g0 = *(const float4*)(g + sl*32 + u*8);
        float4 g1 = *(const float4*)(g + sl*32 + u*8 + 4);
        float4 b0 = *(const float4*)(bta + sl*32 + u*8);
        float4 b1 = *(const float4*)(bta + sl*32 + u*8 + 4);
        const float* gp0 = (const float*)&g0; const float* gp1 = (const float*)&g1;
        const float* bp0 = (const float*)&b0; const float* bp1 = (const float*)&b1;
        ushort8 pk;
        #pragma unroll
        for (int e = 0; e < 4; ++e){
            pk[e]   = f2bf((v[u*8+e]   - mean)*rstd*gp0[e] + bp0[e]);
            pk[4+e] = f2bf((v[u*8+4+e] - mean)*rstd*gp1[e] + bp1[e]);
        }
        int o = sl*4 + u;
        *(ushort8*)(XH + (((size_t)jt*32 + o)*256 + rloc)*8) = pk;
    }
}

// ---------------- per-iter: q = LN_s(slots) @ Wq + bq  (grid (B,8)) ----------------
__global__ void q_kernel(const float* __restrict__ slots, const float* __restrict__ Wq,
                         const float* __restrict__ bq, const float* __restrict__ gs,
                         const float* __restrict__ bs, float* __restrict__ qout){
    __shared__ float sn[8][264];
    const int t = threadIdx.x, b = blockIdx.x, qg = blockIdx.y;
    const int i = t >> 5, c0 = (t & 31) * 8;
    {
        const float* sp = slots + ((size_t)b*K_ + i) * C_ + c0;
        float v[8] __attribute__((aligned(16)));
        *(float4*)v       = *(const float4*)sp;
        *(float4*)(v + 4) = *(const float4*)(sp + 4);
        float sum = 0.f, sq = 0.f;
        #pragma unroll
        for (int e = 0; e < 8; ++e){ sum += v[e]; sq += v[e]*v[e]; }
        #pragma unroll
        for (int m = 1; m < 32; m <<= 1){ sum += __shfl_xor(sum, m); sq += __shfl_xor(sq, m); }
        float mean = sum * (1.f/256.f);
        float rstd = rsqrtf(sq * (1.f/256.f) - mean*mean + 1e-5f);
        #pragma unroll
        for (int e = 0; e < 8; ++e){
            int c = c0 + e;
            sn[i][c] = (v[e] - mean) * rstd * gs[c] + bs[c];
        }
    }
    __syncthreads();
    const int col = qg*32 + (t & 31);
    float acc = bq[col];
    #pragma unroll 4
    for (int c = 0; c < 256; ++c)
        acc += sn[i][c] * Wq[(size_t)c*256 + col];
    qout[((size_t)b*K_ + i)*C_ + col] = acc;
}

// ---------------- per-iter: q~ = SCALE * q @ WkT; qb = SCALE * q . bk  (grid (B,8)) ----------------
__global__ void qt_kernel(const float* __restrict__ qv, const float* __restrict__ WkT,
                          const float* __restrict__ bk, float* __restrict__ qtb,
                          float* __restrict__ qbb){
    __shared__ float qs[8][264];
    const int t = threadIdx.x, b = blockIdx.x, dg = blockIdx.y;
    const int i = t >> 5, c0 = (t & 31) * 8;
    {
        const float* qp = qv + ((size_t)b*K_ + i)*C_ + c0;
        *(float4*)&qs[i][c0]     = *(const float4*)qp;
        *(float4*)&qs[i][c0 + 4] = *(const float4*)(qp + 4);
    }
    __syncthreads();
    const int dcol = dg*32 + (t & 31);
    float acc = 0.f;
    #pragma unroll 4
    for (int c = 0; c < 256; ++c)
        acc += qs[i][c] * WkT[(size_t)c*256 + dcol];
    qtb[((size_t)b*K_ + i)*C_ + dcol] = acc * SCALE_;
    if (dg == 0){
        const int lane = t & 31;
        float pb = 0.f;
        #pragma unroll
        for (int e = 0; e < 8; ++e) pb += qs[i][lane*8 + e] * bk[lane*8 + e];
        #pragma unroll
        for (int m = 1; m < 32; m <<= 1) pb += __shfl_xor(pb, m);
        if (lane == 0) qbb[(size_t)b*K_ + i] = pb * SCALE_;
    }
}

// ---------------- per-iter: attn over x_hat basis (grid (B,16), 256 j per block) ----------------
__global__ __launch_bounds__(256, 4)
void attn_kernel(const unsigned short* __restrict__ XH, const float* __restrict__ qt,
                 const float* __restrict__ qb, float* __restrict__ Spart,
                 float* __restrict__ Upart){
    __shared__ float qts[8][264];                    // [i][0..255]=q~, [256]=qb
    __shared__ __align__(16) unsigned short ps[256*8];   // p bf16
    __shared__ __align__(16) unsigned short vbuf[32*256];  // swizzled x_hat chunk
    __shared__ float swred[4][9];
    const int t = threadIdx.x, b = blockIdx.x, jb = blockIdx.y;
    const unsigned short* XB = XH + (size_t)(b*16 + jb) * 65536;
    {
        const int i = t >> 5, c0 = (t & 31) * 8;
        const float* qp = qt + ((size_t)b*K_ + i)*C_ + c0;
        *(float4*)&qts[i][c0]     = *(const float4*)qp;
        *(float4*)&qts[i][c0 + 4] = *(const float4*)(qp + 4);
        if ((t & 31) == 0) qts[i][256] = qb[(size_t)b*K_ + i];
    }
    __syncthreads();
    // ---- QK: thread t owns j = t; fully coalesced streaming of x_hat ----
    float d[8];
    #pragma unroll
    for (int i = 0; i < 8; ++i) d[i] = qts[i][256];
    for (int o = 0; o < 32; ++o){
        ushort8 xv = *(const ushort8*)(XB + ((size_t)o*256 + t)*8);
        float xf[8];
        #pragma unroll
        for (int e = 0; e < 8; ++e) xf[e] = bf2f(xv[e]);
        #pragma unroll
        for (int i = 0; i < 8; ++i){
            const float4 qa = *(const float4*)&qts[i][o*8];
            const float4 qc = *(const float4*)&qts[i][o*8 + 4];
            d[i] += qa.x*xf[0] + qa.y*xf[1] + qa.z*xf[2] + qa.w*xf[3]
                  + qc.x*xf[4] + qc.y*xf[5] + qc.z*xf[6] + qc.w*xf[7];
        }
    }
    // ---- thread-local softmax over 8 slots (+EPS) ----
    float mx = d[0];
    #pragma unroll
    for (int i = 1; i < 8; ++i) mx = fmaxf(mx, d[i]);
    float e8[8], se = 0.f;
    #pragma unroll
    for (int i = 0; i < 8; ++i){ e8[i] = __expf(d[i] - mx); se += e8[i]; }
    float inv = 1.f / se;
    float p[8];
    #pragma unroll
    for (int i = 0; i < 8; ++i) p[i] = e8[i]*inv + EPS_;
    {
        ushort8 pp;
        #pragma unroll
        for (int i = 0; i < 8; ++i) pp[i] = f2bf(p[i]);
        *(ushort8*)&ps[t*8] = pp;
    }
    #pragma unroll
    for (int i = 0; i < 8; ++i){
        float s = p[i];
        #pragma unroll
        for (int m = 1; m < 64; m <<= 1) s += __shfl_xor(s, m);
        if ((t & 63) == 0) swred[t >> 6][i] = s;
    }
    __syncthreads();    // ps + swred ready
    if (t < 8)
        Spart[((size_t)b*16 + jb)*8 + t] = swred[0][t] + swred[1][t] + swred[2][t] + swred[3][t];
    // ---- PV: u[islot][cg*8..+8) over all 256 j; x_hat restaged via swizzled LDS ----
    const int islot = t >> 5, cg = t & 31;
    const int r = t >> 3, sl = t & 7;
    f32x4 u0 = (f32x4){0.f,0.f,0.f,0.f}, u1 = (f32x4){0.f,0.f,0.f,0.f};
    for (int ch = 0; ch < 8; ++ch){
        #pragma unroll
        for (int uu = 0; uu < 4; ++uu){
            int o = sl + 8*uu;
            ushort8 xv = *(const ushort8*)(XB + ((size_t)o*256 + ch*32 + r)*8);
            int phys = (o & 24) | ((o & 7) ^ (r & 7));
            *(ushort8*)&vbuf[r*256 + phys*8] = xv;
        }
        __syncthreads();
        #pragma unroll 4
        for (int jj = 0; jj < 32; ++jj){
            float pw = bf2f(ps[(ch*32 + jj)*8 + islot]);
            int pc = (cg & 24) | ((cg & 7) ^ (jj & 7));
            ushort8 vv = *(const ushort8*)&vbuf[jj*256 + pc*8];
            u0[0] += pw * bf2f(vv[0]); u0[1] += pw * bf2f(vv[1]);
            u0[2] += pw * bf2f(vv[2]); u0[3] += pw * bf2f(vv[3]);
            u1[0] += pw * bf2f(vv[4]); u1[1] += pw * bf2f(vv[5]);
            u1[2] += pw * bf2f(vv[6]); u1[3] += pw * bf2f(vv[7]);
        }
        __syncthreads();
    }
    {
        float* up = Upart + (((size_t)(b*16 + jb))*8 + islot)*C_ + cg*8;
        float4 o0; o0.x = u0[0]; o0.y = u0[1]; o0.z = u0[2]; o0.w = u0[3];
        float4 o1; o1.x = u1[0]; o1.y = u1[1]; o1.z = u1[2]; o1.w = u1[3];
        *(float4*)up       = o0;
        *(float4*)(up + 4) = o1;
    }
}

// ---------------- per-iter: usum = (sum_jb Upart) / S  (grid (B,4)) ----------------
__global__ void uvred_kernel(const float* __restrict__ Spart, const float* __restrict__ Upart,
                             float* __restrict__ usum){
    const int t = threadIdx.x, b = blockIdx.x, cq = blockIdx.y;
    const int i = t >> 5, c = cq*64 + (t & 31)*2;
    float a0 = 0.f, a1 = 0.f, S = 0.f;
    for (int jb = 0; jb < 16; ++jb){
        const float* up = Upart + (((size_t)(b*16 + jb))*8 + i)*C_ + c;
        float2 u2 = *(const float2*)up;
        a0 += u2.x; a1 += u2.y;
        S += Spart[((size_t)b*16 + jb)*8 + i];
    }
    float invS = 1.f / S;
    float2 o2; o2.x = a0*invS; o2.y = a1*invS;
    *(float2*)(usum + ((size_t)b*K_ + i)*C_ + c) = o2;
}

// ---------------- per-iter: updates = usum @ Wv + bv  (grid (B,8)) ----------------
__global__ void uvgemm_kernel(const float* __restrict__ usum, const float* __restrict__ Wv,
                              const float* __restrict__ bv, float* __restrict__ updates){
    __shared__ float us[8][264];
    const int t = threadIdx.x, b = blockIdx.x, og = blockIdx.y;
    const int i = t >> 5, c0 = (t & 31) * 8;
    {
        const float* up = usum + ((size_t)b*K_ + i)*C_ + c0;
        *(float4*)&us[i][c0]     = *(const float4*)up;
        *(float4*)&us[i][c0 + 4] = *(const float4*)(up + 4);
    }
    __syncthreads();
    const int col = og*32 + (t & 31);
    float acc = bv[col];
    #pragma unroll 4
    for (int c = 0; c < 256; ++c)
        acc += us[i][c] * Wv[(size_t)c*256 + col];
    updates[((size_t)b*K_ + i)*C_ + col] = acc;
}

// ---------------- per-iter: GRUCell (dense updates)  (grid (B,8)) ----------------
__global__ void gru_kernel(const float* __restrict__ slots, const float* __restrict__ updates,
                           const float* __restrict__ W_ih, const float* __restrict__ b_ih,
                           const float* __restrict__ W_hh, const float* __restrict__ b_hh,
                           float* __restrict__ slots2){
    __shared__ float upd[8][260], sp[8][260];
    const int t = threadIdx.x, b = blockIdx.x, ng = blockIdx.y;
    const int i = t >> 5, c0 = (t & 31) * 8;
    {
        const float* up = updates + ((size_t)b*K_ + i)*C_ + c0;
        float4 u0 = *(const float4*)up;
        float4 u1 = *(const float4*)(up + 4);
        const float* slp = slots + ((size_t)b*K_ + i)*C_ + c0;
        float4 s0v = *(const float4*)slp;
        float4 s1v = *(const float4*)(slp + 4);
        upd[i][c0+0]=u0.x; upd[i][c0+1]=u0.y; upd[i][c0+2]=u0.z; upd[i][c0+3]=u0.w;
        upd[i][c0+4]=u1.x; upd[i][c0+5]=u1.y; upd[i][c0+6]=u1.z; upd[i][c0+7]=u1.w;
        sp[i][c0+0]=s0v.x; sp[i][c0+1]=s0v.y; sp[i][c0+2]=s0v.z; sp[i][c0+3]=s0v.w;
        sp[i][c0+4]=s1v.x; sp[i][c0+5]=s1v.y; sp[i][c0+6]=s1v.z; sp[i][c0+7]=s1v.w;
    }
    __syncthreads();
    const int n = ng*32 + (t & 31);
    float xr = b_ih[n], xz = b_ih[256+n], xn = b_ih[512+n];
    float hr = b_hh[n], hz = b_hh[256+n], hn = b_hh[512+n];
    #pragma unroll 2
    for (int c = 0; c < 256; ++c){
        float uv = upd[i][c], sv = sp[i][c];
        const float* wi = W_ih + (size_t)c * 768 + n;
        const float* wh = W_hh + (size_t)c * 768 + n;
        xr += uv*wi[0];   xz += uv*wi[256]; xn += uv*wi[512];
        hr += sv*wh[0];   hz += sv*wh[256]; hn += sv*wh[512];
    }
    float rv = 1.f/(1.f + __expf(-(xr + hr)));
    float zv = 1.f/(1.f + __expf(-(xz + hz)));
    float nn = tanhf(xn + rv*hn);
    float o  = (1.f - zv)*nn + zv*sp[i][n];
    slots2[((size_t)b*K_ + i)*C_ + n] = o;
}

// ---------------- per-iter: FFN part 1 (grid (B,8)) ----------------
__global__ void ffn1_kernel(const float* __restrict__ slots2, const float* __restrict__ gf,
                            const float* __restrict__ bf, const float* __restrict__ W1,
                            const float* __restrict__ b1, float* __restrict__ hbuf){
    __shared__ float pre[8][264];
    const int t = threadIdx.x, b = blockIdx.x, hg = blockIdx.y;
    const int i = t >> 5, c0 = (t & 31) * 8;
    {
        const float* spt = slots2 + ((size_t)b*K_ + i)*C_ + c0;
        float v[8] __attribute__((aligned(16)));
        *(float4*)v       = *(const float4*)spt;
        *(float4*)(v + 4) = *(const float4*)(spt + 4);
        float sum = 0.f, sq = 0.f;
        #pragma unroll
        for (int e = 0; e < 8; ++e){ sum += v[e]; sq += v[e]*v[e]; }
        #pragma unroll
        for (int m = 1; m < 32; m <<= 1){ sum += __shfl_xor(sum, m); sq += __shfl_xor(sq, m); }
        float mean = sum * (1.f/256.f);
        float rstd = rsqrtf(sq * (1.f/256.f) - mean*mean + 1e-5f);
        #pragma unroll
        for (int e = 0; e < 8; ++e){
            int c = c0 + e;
            pre[i][c] = (v[e] - mean) * rstd * gf[c] + bf[c];
        }
    }
    __syncthreads();
    const int hcol = hg*32 + (t & 31);
    float acc = b1[hcol];
    #pragma unroll 4
    for (int c = 0; c < 256; ++c)
        acc += pre[i][c] * W1[(size_t)c*256 + hcol];
    hbuf[((size_t)b*K_ + i)*C_ + hcol] = fmaxf(acc, 0.f);
}

// ---------------- per-iter: FFN part 2 (grid (B,8)) ----------------
__global__ void ffn2_kernel(const float* __restrict__ slots2, const float* __restrict__ hbuf,
                            const float* __restrict__ W2, const float* __restrict__ b2,
                            float* __restrict__ slots, float* __restrict__ dout){
    __shared__ float hs[8][264];
    const int t = threadIdx.x, b = blockIdx.x, og = blockIdx.y;
    const int i = t >> 5, c0 = (t & 31) * 8;
    {
        const float* hp = hbuf + ((size_t)b*K_ + i)*C_ + c0;
        *(float4*)&hs[i][c0]     = *(const float4*)hp;
        *(float4*)&hs[i][c0 + 4] = *(const float4*)(hp + 4);
    }
    __syncthreads();
    const int ocol = og*32 + (t & 31);
    float acc = b2[ocol];
    #pragma unroll 4
    for (int m = 0; m < 256; ++m)
        acc += hs[i][m] * W2[(size_t)m*256 + ocol];
    size_t off = ((size_t)b*K_ + i)*C_ + ocol;
    float val = slots2[off] + acc;
    slots[off] = val;
    dout[off]  = val;
}

extern "C" void kernel_launch(void* const* d_in, const int* in_sizes, int n_in,
                              void* d_out, int out_size, void* d_ws, size_t ws_size,
                              hipStream_t stream){
    const float* inputs = (const float*)d_in[0];
    const float* noise  = (const float*)d_in[1];
    const float* mu     = (const float*)d_in[2];
    const float* lsig   = (const float*)d_in[3];
    const float* g_in   = (const float*)d_in[4];
    const float* b_in   = (const float*)d_in[5];
    const float* g_s    = (const float*)d_in[6];
    const float* b_s    = (const float*)d_in[7];
    const float* g_ff   = (const float*)d_in[8];
    const float* b_ff   = (const float*)d_in[9];
    const float* Wq     = (const float*)d_in[10];
    const float* bq     = (const float*)d_in[11];
    const float* Wk     = (const float*)d_in[12];
    const float* bk     = (const float*)d_in[13];
    const float* Wv     = (const float*)d_in[14];
    const float* bv     = (const float*)d_in[15];
    const float* W_ih   = (const float*)d_in[16];
    const float* b_ih   = (const float*)d_in[17];
    const float* W_hh   = (const float*)d_in[18];
    const float* b_hh   = (const float*)d_in[19];
    const float* W1     = (const float*)d_in[20];
    const float* b1     = (const float*)d_in[21];
    const float* W2     = (const float*)d_in[22];
    const float* b2     = (const float*)d_in[23];

    char* ws = (char*)d_ws;
    unsigned short* XH  = (unsigned short*)(ws);               // 128 MB
    float* Upart        = (float*)(ws + ((size_t)128 << 20));  // 8 MB
    float* Spart        = (float*)(ws + ((size_t)136 << 20));  // 8 KB
    float* qbuf         = (float*)(ws + ((size_t)137 << 20));  // 512 KB
    float* qtbuf        = (float*)(ws + ((size_t)138 << 20));  // 512 KB
    float* qbbuf        = (float*)(ws + ((size_t)139 << 20));  // 2 KB
    float* usum         = (float*)(ws + ((size_t)140 << 20));  // 512 KB
    float* updates      = (float*)(ws + ((size_t)141 << 20));  // 512 KB
    float* slots        = (float*)(ws + ((size_t)142 << 20));  // 512 KB
    float* slots2       = (float*)(ws + ((size_t)143 << 20));  // 512 KB
    float* hbuf         = (float*)(ws + ((size_t)144 << 20));  // 512 KB
    float* WkT          = (float*)(ws + ((size_t)145 << 20));  // 256 KB

    prep_kernel<<<512, 256, 0, stream>>>(mu, lsig, noise, Wk, slots, WkT);
    ln_kernel<<<M_/32, 256, 0, stream>>>(inputs, g_in, b_in, XH);
    for (int it = 0; it < ITERS_; ++it){
        q_kernel<<<dim3(B_, 8), 256, 0, stream>>>(slots, Wq, bq, g_s, b_s, qbuf);
        qt_kernel<<<dim3(B_, 8), 256, 0, stream>>>(qbuf, WkT, bk, qtbuf, qbbuf);
        attn_kernel<<<dim3(B_, 16), 256, 0, stream>>>(XH, qtbuf, qbbuf, Spart, Upart);
        uvred_kernel<<<dim3(B_, 4), 256, 0, stream>>>(Spart, Upart, usum);
        uvgemm_kernel<<<dim3(B_, 8), 256, 0, stream>>>(usum, Wv, bv, updates);
        gru_kernel<<<dim3(B_, 8), 256, 0, stream>>>(slots, updates, W_ih, b_ih, W_hh, b_hh, slots2);
        ffn1_kernel<<<dim3(B_, 8), 256, 0, stream>>>(slots2, g_ff, b_ff, W1, b1, hbuf);
        ffn2_kernel<<<dim3(B_, 8), 256, 0, stream>>>(slots2, hbuf, W2, b2, slots, (float*)d_out);
    }
}